// Round 14
// baseline (188.515 us; speedup 1.0000x reference)
//
#include <hip/hip_runtime.h>

// NCC loss, win=9, (1,1,160,192,224) fp32 -> scalar. Round 21: WAVE-AUTONOMOUS.
// R9-R20: six structural experiments around the block-barrier pipeline all
// null/regress at ~58.6us, VALU ~40%. Per-voxel-slice wall 3.86cy vs 1.54cy
// VALU -> the gap is cross-wave coupling at 37 block-wide barriers/chunk.
// R21 removes ALL intra-kernel synchronization: each 64-lane wave owns an
// 8x8xD output column, block = 1 wave, private LDS, ZERO barriers:
//   per slice z: 1 f4/lane/array global load (16x16 halo tile)
//     -> transposed raw LDS [col16][row16] cs=17 (writes/reads <=2-way)
//     -> W: lane (row16=lane>>2, g=lane&3): 10 raw/array (ds_read2 x5),
//        2 out-cols x 5ch sliding sums -> Wbuf [ch][row16][col8] (2-way free)
//     -> H: lane (fc=lane&7, fr=lane>>3): 9-tap column sum per ch (read2)
//     -> D-ring(9) + cc in regs (unchanged from R12).
// Same-wave LDS ops are pipe-ordered -> no s_barrier, no manual waitcnt;
// compiler inserts data-dep lgkmcnt only. 16 independent waves/CU (reg-cap)
// hide each other's latency by TLP instead of lockstep.
// VALU/voxel ~= R12 (CU-normalized 1.3 vs 1.54 cy); LDS ~44 inst/lane-slice.
// LDS 4.7KB/block; grid 28x24x6 = 4032 one-wave blocks = 15.75 waves/CU.
// Tripwire: WRITE_SIZE MB-scale => spill (ring45+temps vs 128-reg cap).

#define DD 160
#define HH 192
#define WW 224
#define W4 56                 // WW/4
#define SLICE (HH * WW)
#define S4 (SLICE / 4)
#define NVOX (DD * SLICE)
#define DCH 28                // grid.z = 6
#define ITERS (DCH + 8)       // 36 = 4 * 9 (phase-static ring)
#define RAW_CS 17             // raw col stride (dwords): <=2-way on all paths
#define WB_RS 8               // Wbuf row stride
#define WB_CH 128             // Wbuf channel stride = 16 rows * 8 cols
#define EPS 1e-5f
#define INV_WSUM (1.0f / 729.0f)

__global__ __launch_bounds__(64, 4) void ncc_fused(const float* __restrict__ I,
                                                   const float* __restrict__ J,
                                                   float* __restrict__ out) {
    __shared__ float rawI[16 * RAW_CS];   // [col16][row16], 1088 B
    __shared__ float rawJ[16 * RAW_CS];   // 1088 B
    __shared__ float WB[5 * WB_CH];       // [ch][row16][col8], 2560 B

    const int lane = threadIdx.x;         // 0..63, one wave
    const int wlo = blockIdx.x * 8;
    const int hlo = blockIdx.y * 8;
    const int dlo = blockIdx.z * DCH;

    // load / W mapping: (lrow = lane>>2 in 0..15, lg = lane&3 in 0..3)
    const int lrow = lane >> 2, lg = lane & 3;
    const int gh = hlo - 4 + lrow;                  // raw row (halo'd)
    const int gf = (wlo >> 2) - 1 + lg;             // raw f4-col (halo'd)
    const bool rcok = (gh >= 0) && (gh < HH) && (gf >= 0) && (gf < W4);

    // H / output mapping: voxel (col = wlo+fc, row = hlo+fr)
    const int fc = lane & 7, fr = lane >> 3;

    const float4* Iv = (const float4*)I;
    const float4* Jv = (const float4*)J;

    float4 pa, pb;   // prefetched raw f4 (next slice)
    auto issue_load = [&](int z) {       // zeros if OOB (zero-pad semantics)
        pa = make_float4(0.f, 0.f, 0.f, 0.f);
        pb = make_float4(0.f, 0.f, 0.f, 0.f);
        if (z >= 0 && z < DD && rcok) {
            const int idx = z * S4 + gh * W4 + gf;
            pa = Iv[idx]; pb = Jv[idx];
        }
    };
    auto raw_write = [&]() {   // transposed store: cols 4lg..4lg+3, row lrow
        float* pI = rawI + (4 * lg) * RAW_CS + lrow;
        float* pJ = rawJ + (4 * lg) * RAW_CS + lrow;
        pI[0] = pa.x; pI[RAW_CS] = pa.y; pI[2 * RAW_CS] = pa.z; pI[3 * RAW_CS] = pa.w;
        pJ[0] = pb.x; pJ[RAW_CS] = pb.y; pJ[2 * RAW_CS] = pb.z; pJ[3 * RAW_CS] = pb.w;
    };

    float q0[9], q1[9], q2[9], q3[9], q4[9];
    #pragma unroll
    for (int k = 0; k < 9; ++k) { q0[k]=0.f; q1[k]=0.f; q2[k]=0.f; q3[k]=0.f; q4[k]=0.f; }
    float r0=0.f, r1=0.f, r2=0.f, r3=0.f, r4=0.f;
    float acc = 0.f;

    // prologue: raw(z0) -> LDS; prefetch z0+1
    issue_load(dlo - 4);
    raw_write();
    issue_load(dlo - 3);

    #pragma unroll 1
    for (int g = 0; g < 4; ++g) {
        #pragma unroll
        for (int ph = 0; ph < 9; ++ph) {
            const int j = 9 * g + ph;
            const int z = dlo - 4 + j;               // slice processed now
            const bool zval = (z >= 0) && (z < DD);  // block-uniform

            float w0=0.f, w1=0.f, w2=0.f, w3=0.f, w4=0.f;
            if (zval) {
                // ---- W: out cols 2lg,2lg+1 at row lrow, 5 channels ----
                const float* rI = rawI + (2 * lg) * RAW_CS + lrow;
                const float* rJ = rawJ + (2 * lg) * RAW_CS + lrow;
                float a[10], b[10];
                #pragma unroll
                for (int k = 0; k < 10; ++k) {       // col-strided: read2 pairs
                    a[k] = rI[k * RAW_CS];
                    b[k] = rJ[k * RAW_CS];
                }
                float sI = a[0], sJ = b[0];
                float sII = a[0]*a[0], sJJ = b[0]*b[0], sIJ = a[0]*b[0];
                #pragma unroll
                for (int k = 1; k < 9; ++k) {
                    sI  += a[k];        sJ  += b[k];
                    sII += a[k]*a[k];   sJJ += b[k]*b[k];   sIJ += a[k]*b[k];
                }
                float* wb = WB + lrow * WB_RS + 2 * lg;
                wb[0]            = sI;
                wb[1]            = sI  + a[9]      - a[0];
                wb[WB_CH]        = sJ;
                wb[WB_CH + 1]    = sJ  + b[9]      - b[0];
                wb[2*WB_CH]      = sII;
                wb[2*WB_CH + 1]  = sII + a[9]*a[9] - a[0]*a[0];
                wb[3*WB_CH]      = sJJ;
                wb[3*WB_CH + 1]  = sJJ + b[9]*b[9] - b[0]*b[0];
                wb[4*WB_CH]      = sIJ;
                wb[4*WB_CH + 1]  = sIJ + a[9]*b[9] - a[0]*b[0];

                // ---- H: 9-tap column sum at (fc, fr), 5 channels ----
                // (same-wave LDS pipe order: writes above complete first)
                const float* hb = WB + fr * WB_RS + fc;
                float h0=0.f, h1=0.f, h2=0.f, h3=0.f, h4=0.f;
                #pragma unroll
                for (int k = 0; k < 9; ++k) {        // offsets k*8: read2 pairs
                    h0 += hb[k * WB_RS];
                    h1 += hb[WB_CH   + k * WB_RS];
                    h2 += hb[2*WB_CH + k * WB_RS];
                    h3 += hb[3*WB_CH + k * WB_RS];
                    h4 += hb[4*WB_CH + k * WB_RS];
                }
                w0 = h0; w1 = h1; w2 = h2; w3 = h3; w4 = h4;
            }

            // ---- D-ring + cc (identical math to R12) ----
            r0 += w0 - q0[ph]; q0[ph] = w0;
            r1 += w1 - q1[ph]; q1[ph] = w1;
            r2 += w2 - q2[ph]; q2[ph] = w2;
            r3 += w3 - q3[ph]; q3[ph] = w3;
            r4 += w4 - q4[ph]; q4[ph] = w4;

            if (j >= 8 && (dlo + j - 8) < DD) {      // overhang guard to 167
                float cross = r4 - r0 * r1 * INV_WSUM;
                float iv    = r2 - r0 * r0 * INV_WSUM;
                float jv    = r3 - r1 * r1 * INV_WSUM;
                acc += cross * cross * __builtin_amdgcn_rcpf(iv * jv + EPS);
            }

            // ---- stage raw(z+1), prefetch raw(z+2) ----
            if (j < ITERS - 1) {
                raw_write();          // pipe-ordered after this phase's reads
                issue_load(z + 2);
            }
        }
    }

    // ---- wave reduction -> one atomic (no LDS, no syncthreads) ----
    #pragma unroll
    for (int off = 32; off > 0; off >>= 1) acc += __shfl_down(acc, off, 64);
    if (lane == 0) atomicAdd(out, acc * (-1.0f / (float)NVOX));
}

extern "C" void kernel_launch(void* const* d_in, const int* in_sizes, int n_in,
                              void* d_out, int out_size, void* d_ws, size_t ws_size,
                              hipStream_t stream) {
    const float* I = (const float*)d_in[0];
    const float* J = (const float*)d_in[1];
    float* out = (float*)d_out;

    hipMemsetAsync(d_out, 0, sizeof(float), stream);  // harness re-poisons d_out

    dim3 blk(64, 1, 1);
    dim3 grd(WW / 8, HH / 8, (DD + DCH - 1) / DCH);   // 28 x 24 x 6 = 4032 waves
    ncc_fused<<<grd, blk, 0, stream>>>(I, J, out);
}